// Round 2
// baseline (1221.688 us; speedup 1.0000x reference)
//
#include <hip/hip_runtime.h>
#include <hip/hip_bf16.h>
#include <math.h>

// Problem constants
#define BATCH 64
#define TSEQ  512
#define BT    (BATCH*TSEQ)      // 32768
#define EDIM  300
#define HID   128
#define G4    512               // 4*H
#define KTAG  3

// ---------------------------------------------------------------------------
// Kernel A: fused embedding gather + input GEMM for both directions.
// Computes xW[dir][m][j] = emb[tokens[m]] @ W{f,b} + b{f,b}
// M = 32768 rows, N = 1024 cols (dir*512 + j), K = 300.
// 64x64 tile, 256 threads, 4x4 micro-tile, f32 FMA.
// ---------------------------------------------------------------------------
__global__ __launch_bounds__(256) void embed_gemm(
    const int* __restrict__ tokens, const float* __restrict__ emb,
    const float* __restrict__ Wf, const float* __restrict__ bf,
    const float* __restrict__ Wb, const float* __restrict__ bb,
    float* __restrict__ xW)
{
    const int c0 = blockIdx.x * 64;   // 0..960
    const int m0 = blockIdx.y * 64;   // 0..32704
    const int tid = threadIdx.x;

    __shared__ float As[16][68];      // [k][row], pad 68 for bank spread + 16B align
    __shared__ float Bs[16][68];      // [k][col]
    __shared__ int   toks[64];

    if (tid < 64) toks[tid] = tokens[m0 + tid];
    __syncthreads();

    const int dir = c0 >> 9;          // entire 64-col tile in one direction
    const float* __restrict__ W    = dir ? Wb : Wf;
    const float* __restrict__ bias = dir ? bb : bf;
    const int j0 = c0 & 511;

    const int tx = tid & 15;          // col group (4 cols)
    const int ty = tid >> 4;          // row group (4 rows)

    float acc[4][4] = {};

    for (int k0 = 0; k0 < EDIM; k0 += 16) {
        // A load: kk = tid&15 (consecutive k per 16 threads -> coalesced 64B)
        {
            const int kk = tid & 15, i0 = tid >> 4;
            const int k = k0 + kk;
            #pragma unroll
            for (int r = 0; r < 4; ++r) {
                const int i = i0 + r * 16;
                As[kk][i] = (k < EDIM) ? emb[(size_t)toks[i] * EDIM + k] : 0.f;
            }
        }
        // B load: cc = tid&63 consecutive cols -> coalesced 256B
        {
            const int cc = tid & 63, kb = tid >> 6;
            #pragma unroll
            for (int r = 0; r < 4; ++r) {
                const int kk = kb + r * 4;
                const int k = k0 + kk;
                Bs[kk][cc] = (k < EDIM) ? W[(size_t)k * G4 + j0 + cc] : 0.f;
            }
        }
        __syncthreads();
        #pragma unroll
        for (int kk = 0; kk < 16; ++kk) {
            const float4 a = *(const float4*)&As[kk][ty * 4];
            const float4 b = *(const float4*)&Bs[kk][tx * 4];
            const float av[4] = {a.x, a.y, a.z, a.w};
            const float bv[4] = {b.x, b.y, b.z, b.w};
            #pragma unroll
            for (int i = 0; i < 4; ++i)
                #pragma unroll
                for (int j = 0; j < 4; ++j)
                    acc[i][j] += av[i] * bv[j];
        }
        __syncthreads();
    }

    // epilogue: +bias, float4 stores (coalesced within a wave)
    const float4 b4 = *(const float4*)&bias[j0 + tx * 4];
    const size_t obase = (size_t)dir * BT * G4;
    #pragma unroll
    for (int i = 0; i < 4; ++i) {
        const int m = m0 + ty * 4 + i;
        float4 v;
        v.x = acc[i][0] + b4.x;
        v.y = acc[i][1] + b4.y;
        v.z = acc[i][2] + b4.z;
        v.w = acc[i][3] + b4.w;
        *(float4*)&xW[obase + (size_t)m * G4 + j0 + tx * 4] = v;
    }
}

// ---------------------------------------------------------------------------
// Fast activations: v_exp_f32 / v_rcp_f32 based, ~1-2 ulp, no libm branches.
// ---------------------------------------------------------------------------
__device__ __forceinline__ float fsig(float x) {
    return __builtin_amdgcn_rcpf(1.f + __expf(-x));
}
__device__ __forceinline__ float ftanh(float x) {
    x = fminf(15.f, fmaxf(-15.f, x));          // avoid inf/inf (|z| << 15 anyway)
    const float e = __expf(2.f * x);
    return (e - 1.f) * __builtin_amdgcn_rcpf(e + 1.f);
}

// ---------------------------------------------------------------------------
// Kernel B: LSTM recurrence, one block per (dir, batch) = 128 blocks.
// 256 threads (4 waves); thread owns TWO U columns (one gate-pair of a unit):
//   pair 0 (lanes 0-31 of wave): gates (i, g) of unit j
//   pair 1 (lanes 32-63):        gates (f, o) of unit j      (j = 32*w + l&31)
// -> 256 weight VGPRs/thread; full h[128] read once per thread per step
//    (halves the LDS broadcast instruction count vs 512-thread version).
// Gate exchange via __shfl_xor(.,32) (same wave); cell update computed
// redundantly in both partner lanes (bitwise identical). Double-buffered
// h in LDS -> single barrier per step, no z round-trip.
// dir=1 walks t backwards; h stored at ORIGINAL time index.
// ---------------------------------------------------------------------------
__global__ __launch_bounds__(256, 1) void lstm_kernel(
    const float* __restrict__ Uf, const float* __restrict__ Ub,
    const float* __restrict__ xW, float* __restrict__ hs)
{
    const int blk = blockIdx.x;       // 0..127
    const int dir = blk >> 6;
    const int tid = threadIdx.x;      // 0..255
    const int w    = tid >> 6;
    const int l    = tid & 63;
    const int pair = l >> 5;                    // 0:(i,g)  1:(f,o)
    const int j    = (w << 5) + (l & 31);       // hidden unit 0..127
    const int col_a = (pair ? 128 : 0) + j;     // i- or f-gate column
    const int col_b = (pair ? 384 : 256) + j;   // g- or o-gate column
    const float* __restrict__ U = dir ? Ub : Uf;

    float ua[128], ub[128];
    #pragma unroll
    for (int k = 0; k < 128; ++k) {
        ua[k] = U[k * G4 + col_a];
        ub[k] = U[k * G4 + col_b];
    }

    __shared__ float hbuf[2][HID];
    if (tid < HID) hbuf[0][tid] = 0.f;
    float c = 0.f;

    const float* __restrict__ xW_blk = xW + (size_t)blk * (TSEQ * G4);
    float* __restrict__ hs_blk = hs + (size_t)blk * (TSEQ * HID);
    __syncthreads();

    int tt = dir ? (TSEQ - 1) : 0;
    const int tstep = dir ? -1 : 1;
    float xa = xW_blk[tt * G4 + col_a];
    float xb = xW_blk[tt * G4 + col_b];

    for (int t = 0; t < TSEQ; ++t) {
        const int p = t & 1;
        const int ttn = tt + tstep;
        float xa_n = 0.f, xb_n = 0.f;
        if (t < TSEQ - 1) {                      // prefetch next step's xW
            xa_n = xW_blk[ttn * G4 + col_a];
            xb_n = xW_blk[ttn * G4 + col_b];
        }

        float za = xa, zb = xb;
        #pragma unroll
        for (int k = 0; k < 128; k += 4) {
            const float4 hv = *(const float4*)&hbuf[p][k];   // broadcast reads
            za += hv.x*ua[k] + hv.y*ua[k+1] + hv.z*ua[k+2] + hv.w*ua[k+3];
            zb += hv.x*ub[k] + hv.y*ub[k+1] + hv.z*ub[k+2] + hv.w*ub[k+3];
        }

        // exchange with partner lane (l ^ 32): pair0 holds (zi,zg), pair1 (zf,zo)
        const float za_p = __shfl_xor(za, 32);
        const float zb_p = __shfl_xor(zb, 32);
        const float zi = pair ? za_p : za;
        const float zf = pair ? za   : za_p;
        const float zg = pair ? zb_p : zb;
        const float zo = pair ? zb   : zb_p;

        const float ig = fsig(zi);
        const float fg = fsig(zf);
        const float gg = ftanh(zg);
        const float og = fsig(zo);
        c = fg * c + ig * gg;                    // identical in both partner lanes
        const float h = og * ftanh(c);

        if (!pair) {                             // one writer per unit
            hbuf[p ^ 1][j] = h;
            hs_blk[tt * HID + j] = h;            // 128B contiguous per wave
        }
        __syncthreads();
        xa = xa_n; xb = xb_n; tt = ttn;
    }
}

// ---------------------------------------------------------------------------
// Kernel C: fold dense + CRF inner kernel: Wd2 = Wd @ crf_W, b2 = bd@crf_W+crf_b
// ---------------------------------------------------------------------------
__global__ void prep_kernel(const float* __restrict__ Wd, const float* __restrict__ bd,
                            const float* __restrict__ crf_W, const float* __restrict__ crf_b,
                            float* __restrict__ Wd2, float* __restrict__ b2)
{
    const int u = threadIdx.x;        // 256 threads
    #pragma unroll
    for (int k = 0; k < KTAG; ++k) {
        float s = 0.f;
        #pragma unroll
        for (int jj = 0; jj < KTAG; ++jj) s += Wd[u * KTAG + jj] * crf_W[jj * KTAG + k];
        Wd2[u * KTAG + k] = s;
    }
    if (u < KTAG) {
        float s = crf_b[u];
        #pragma unroll
        for (int jj = 0; jj < KTAG; ++jj) s += bd[jj] * crf_W[jj * KTAG + u];
        b2[u] = s;
    }
}

// ---------------------------------------------------------------------------
// Kernel D: potentials. One wave per (b,t): pot = [h_f|h_b] @ Wd2 + b2 (+bounds)
// ---------------------------------------------------------------------------
__global__ __launch_bounds__(256) void pot_kernel(
    const float* __restrict__ hs, const float* __restrict__ Wd2,
    const float* __restrict__ b2, const float* __restrict__ left_b,
    const float* __restrict__ right_b, float* __restrict__ pot)
{
    const int wave = blockIdx.x * 4 + (threadIdx.x >> 6);  // (b,t) index
    const int lane = threadIdx.x & 63;
    const int b = wave >> 9, t = wave & 511;

    const float* __restrict__ hf = hs + ((size_t)b * TSEQ + t) * HID;
    const float* __restrict__ hb = hf + (size_t)BATCH * TSEQ * HID;

    const float x0 = hf[lane], x1 = hf[lane + 64];
    const float x2 = hb[lane], x3 = hb[lane + 64];

    float a[KTAG];
    #pragma unroll
    for (int k = 0; k < KTAG; ++k)
        a[k] = x0 * Wd2[lane * KTAG + k] + x1 * Wd2[(lane + 64) * KTAG + k]
             + x2 * Wd2[(lane + 128) * KTAG + k] + x3 * Wd2[(lane + 192) * KTAG + k];

    #pragma unroll
    for (int off = 32; off; off >>= 1) {
        a[0] += __shfl_xor(a[0], off);
        a[1] += __shfl_xor(a[1], off);
        a[2] += __shfl_xor(a[2], off);
    }

    if (lane < KTAG) {
        float v = a[lane] + b2[lane];
        if (t == 0)        v += left_b[lane];
        if (t == TSEQ - 1) v += right_b[lane];
        pot[(size_t)wave * KTAG + lane] = v;
    }
}

// ---------------------------------------------------------------------------
// Kernel E: Viterbi decode, one block per batch. Exact first-max-wins argmax
// semantics (matches jnp.argmax). Backpointers packed 2 bits/state in LDS.
// Decoded tags written as float32.
// ---------------------------------------------------------------------------
__global__ __launch_bounds__(64) void viterbi_kernel(
    const float* __restrict__ pot, const float* __restrict__ chain,
    float* __restrict__ decoded)
{
    const int b = blockIdx.x;
    const int lane = threadIdx.x;

    __shared__ float p[TSEQ][KTAG];
    __shared__ int bp[TSEQ - 1];
    __shared__ unsigned char tags[TSEQ];

    const float* __restrict__ pb = pot + (size_t)b * TSEQ * KTAG;
    for (int i = lane; i < TSEQ * KTAG; i += 64) ((float*)p)[i] = pb[i];
    __syncthreads();

    if (lane == 0) {
        float tr[KTAG][KTAG];
        #pragma unroll
        for (int i = 0; i < 9; ++i) tr[i / 3][i % 3] = chain[i];

        float a0 = p[0][0], a1 = p[0][1], a2 = p[0][2];
        for (int t = 1; t < TSEQ; ++t) {
            float n[KTAG]; int bpk[KTAG];
            #pragma unroll
            for (int kn = 0; kn < KTAG; ++kn) {
                const float s0 = a0 + tr[0][kn];
                const float s1 = a1 + tr[1][kn];
                const float s2 = a2 + tr[2][kn];
                float best = s0; int arg = 0;
                if (s1 > best) { best = s1; arg = 1; }
                if (s2 > best) { best = s2; arg = 2; }
                n[kn] = best + p[t][kn];
                bpk[kn] = arg;
            }
            bp[t - 1] = bpk[0] | (bpk[1] << 2) | (bpk[2] << 4);
            a0 = n[0]; a1 = n[1]; a2 = n[2];
        }
        int tag = 0; float best = a0;
        if (a1 > best) { best = a1; tag = 1; }
        if (a2 > best) { best = a2; tag = 2; }
        tags[TSEQ - 1] = (unsigned char)tag;
        for (int t = TSEQ - 2; t >= 0; --t) {
            tag = (bp[t] >> (2 * tag)) & 3;
            tags[t] = (unsigned char)tag;
        }
    }
    __syncthreads();
    for (int t = lane; t < TSEQ; t += 64)
        decoded[(size_t)b * TSEQ + t] = (float)tags[t];
}

// ---------------------------------------------------------------------------
extern "C" void kernel_launch(void* const* d_in, const int* in_sizes, int n_in,
                              void* d_out, int out_size, void* d_ws, size_t ws_size,
                              hipStream_t stream) {
    const int*   tokens  = (const int*)d_in[0];
    const float* emb     = (const float*)d_in[1];
    const float* Wf      = (const float*)d_in[2];
    const float* Uf      = (const float*)d_in[3];
    const float* bf      = (const float*)d_in[4];
    const float* Wb      = (const float*)d_in[5];
    const float* Ub      = (const float*)d_in[6];
    const float* bb      = (const float*)d_in[7];
    const float* Wd      = (const float*)d_in[8];
    const float* bd      = (const float*)d_in[9];
    const float* crf_W   = (const float*)d_in[10];
    const float* crf_b   = (const float*)d_in[11];
    const float* chain   = (const float*)d_in[12];
    const float* left_b  = (const float*)d_in[13];
    const float* right_b = (const float*)d_in[14];

    float* out = (float*)d_out;                    // [0,32768): decoded, then pot
    float* pot = out + BT;

    float* xW  = (float*)d_ws;                     // 2 * 32768 * 512 f32 = 128 MB
    float* hs  = xW + (size_t)2 * BT * G4;         // 2 * 64 * 512 * 128 f32 = 32 MB
    float* Wd2 = hs + (size_t)2 * BATCH * TSEQ * HID;
    float* b2  = Wd2 + 2 * HID * KTAG;

    dim3 gA(1024 / 64, BT / 64);                   // 16 x 512 blocks
    embed_gemm<<<gA, 256, 0, stream>>>(tokens, emb, Wf, bf, Wb, bb, xW);
    prep_kernel<<<1, 256, 0, stream>>>(Wd, bd, crf_W, crf_b, Wd2, b2);
    lstm_kernel<<<128, 256, 0, stream>>>(Uf, Ub, xW, hs);
    pot_kernel<<<BT / 4, 256, 0, stream>>>(hs, Wd2, b2, left_b, right_b, pot);
    viterbi_kernel<<<BATCH, 64, 0, stream>>>(pot, chain, out);
}

// Round 3
// 808.543 us; speedup vs baseline: 1.5110x; 1.5110x over previous
//
#include <hip/hip_runtime.h>
#include <hip/hip_bf16.h>
#include <math.h>

// Problem constants
#define BATCH 64
#define TSEQ  512
#define BT    (BATCH*TSEQ)      // 32768
#define EDIM  300
#define HID   128
#define G4    512               // 4*H
#define KTAG  3

// ---------------------------------------------------------------------------
// Kernel A: fused embedding gather + input GEMM for both directions.
// xW[dir][m][j] = emb[tokens[m]] @ W{f,b} + b{f,b}
// M = 32768, N = 1024 (dir*512 + j), K = 300.
// 128x128 tile, 256 threads, 8x8 micro-tile as 2x2 blocks of 4x4
// (keeps LDS reads conflict-free: float4 at tx*16B and 256B+tx*16B).
// ---------------------------------------------------------------------------
__global__ __launch_bounds__(256) void embed_gemm(
    const int* __restrict__ tokens, const float* __restrict__ emb,
    const float* __restrict__ Wf, const float* __restrict__ bf,
    const float* __restrict__ Wb, const float* __restrict__ bb,
    float* __restrict__ xW)
{
    const int c0 = blockIdx.x * 128;  // 0..896
    const int m0 = blockIdx.y * 128;
    const int tid = threadIdx.x;

    __shared__ __align__(16) float As[8][132];   // [k][row]
    __shared__ __align__(16) float Bs[8][132];   // [k][col]
    __shared__ int toks[128];

    if (tid < 128) toks[tid] = tokens[m0 + tid];
    __syncthreads();

    const int dir = c0 >> 9;          // whole 128-col tile in one direction
    const float* __restrict__ W    = dir ? Wb : Wf;
    const float* __restrict__ bias = dir ? bb : bf;
    const int j0 = c0 & 511;

    const int tx = tid & 15;          // col group
    const int ty = tid >> 4;          // row group

    float acc[2][2][4][4] = {};       // [mi][nj][r][c]

    for (int k0 = 0; k0 < EDIM; k0 += 8) {
        // A load: 128 rows x 8 k; kk = tid&7 consecutive-k, 32 rows/pass
        {
            const int kk = tid & 7, i0 = tid >> 3;
            const int k = k0 + kk;
            #pragma unroll
            for (int rr = 0; rr < 4; ++rr) {
                const int i = i0 + rr * 32;
                As[kk][i] = (k < EDIM) ? emb[(size_t)toks[i] * EDIM + k] : 0.f;
            }
        }
        // B load: 8 k x 128 cols; cc = tid&127 consecutive cols (512B coalesced)
        {
            const int cc = tid & 127, kb = tid >> 7;
            #pragma unroll
            for (int rr = 0; rr < 4; ++rr) {
                const int kk = kb + rr * 2;
                const int k = k0 + kk;
                Bs[kk][cc] = (k < EDIM) ? W[(size_t)k * G4 + j0 + cc] : 0.f;
            }
        }
        __syncthreads();
        #pragma unroll
        for (int kk = 0; kk < 8; ++kk) {
            float a[2][4], b[2][4];
            *(float4*)a[0] = *(const float4*)&As[kk][ty * 4];
            *(float4*)a[1] = *(const float4*)&As[kk][64 + ty * 4];
            *(float4*)b[0] = *(const float4*)&Bs[kk][tx * 4];
            *(float4*)b[1] = *(const float4*)&Bs[kk][64 + tx * 4];
            #pragma unroll
            for (int mi = 0; mi < 2; ++mi)
                #pragma unroll
                for (int nj = 0; nj < 2; ++nj)
                    #pragma unroll
                    for (int r = 0; r < 4; ++r)
                        #pragma unroll
                        for (int cj = 0; cj < 4; ++cj)
                            acc[mi][nj][r][cj] += a[mi][r] * b[nj][cj];
        }
        __syncthreads();
    }

    // epilogue: +bias, float4 stores
    float4 b4[2];
    b4[0] = *(const float4*)&bias[j0 + tx * 4];
    b4[1] = *(const float4*)&bias[j0 + 64 + tx * 4];
    const size_t obase = (size_t)dir * BT * G4;
    #pragma unroll
    for (int mi = 0; mi < 2; ++mi) {
        #pragma unroll
        for (int r = 0; r < 4; ++r) {
            const int m = m0 + mi * 64 + ty * 4 + r;
            #pragma unroll
            for (int nj = 0; nj < 2; ++nj) {
                const float* bb4 = (const float*)&b4[nj];
                float4 v;
                v.x = acc[mi][nj][r][0] + bb4[0];
                v.y = acc[mi][nj][r][1] + bb4[1];
                v.z = acc[mi][nj][r][2] + bb4[2];
                v.w = acc[mi][nj][r][3] + bb4[3];
                *(float4*)&xW[obase + (size_t)m * G4 + j0 + nj * 64 + tx * 4] = v;
            }
        }
    }
}

// ---------------------------------------------------------------------------
// Fast activations: v_exp_f32 / v_rcp_f32 based, ~1-2 ulp, no libm branches.
// ---------------------------------------------------------------------------
__device__ __forceinline__ float fsig(float x) {
    return __builtin_amdgcn_rcpf(1.f + __expf(-x));
}
__device__ __forceinline__ float ftanh(float x) {
    x = fminf(15.f, fmaxf(-15.f, x));          // avoid inf/inf (|z| << 15 anyway)
    const float e = __expf(2.f * x);
    return (e - 1.f) * __builtin_amdgcn_rcpf(e + 1.f);
}

// ---------------------------------------------------------------------------
// Kernel B: LSTM recurrence, one block per (dir, batch) = 128 blocks.
// 512 threads: thread (j2 = tid>>2, ks = tid&3). Thread owns U rows
// [32ks, 32ks+32) for ALL 4 gates of unit j2 -> 128 weight VGPRs.
//   - 8 float4 broadcast LDS reads of h per step (bank-swizzled, conflict-free)
//   - 4 interleaved 32-deep FMA chains (ILP=4, short chain latency)
//   - butterfly reduce over ks-lanes (shfl_xor 1,2; partners in-wave);
//     all 4 partners get bitwise-identical z[4] -> redundant identical c,h
//   - xW: each thread loads ONE value (gate = ks), added pre-butterfly
//   - double-buffered h in LDS -> ONE barrier per step
// dir=1 walks t backwards; h stored at ORIGINAL time index.
// ---------------------------------------------------------------------------
__global__ __launch_bounds__(512, 2) void lstm_kernel(
    const float* __restrict__ Uf, const float* __restrict__ Ub,
    const float* __restrict__ xW, float* __restrict__ hs)
{
    const int blk = blockIdx.x;       // 0..127
    const int dir = blk >> 6;
    const int tid = threadIdx.x;      // 0..511
    const int j2  = tid >> 2;         // hidden unit 0..127
    const int ks  = tid & 3;          // k-quarter
    const float* __restrict__ U = dir ? Ub : Uf;

    // weights: u[g][r] = U[32*ks + r][g*128 + j2]
    float u[4][32];
    #pragma unroll
    for (int g = 0; g < 4; ++g)
        #pragma unroll
        for (int r = 0; r < 32; ++r)
            u[g][r] = U[(size_t)(32 * ks + r) * G4 + g * 128 + j2];

    // h double buffer, padded 8 floats per 32 so the 4 ks-segments start on
    // different banks AND stay 16B aligned: slot(j) = j + (j>>5)*8
    __shared__ __align__(16) float hbuf[2][160];
    if (tid < 128) hbuf[0][tid + (tid >> 5) * 8] = 0.f;
    float c = 0.f;

    const float* __restrict__ xW_blk = xW + (size_t)blk * (TSEQ * G4);
    float* __restrict__ hs_blk = hs + (size_t)blk * (TSEQ * HID);
    __syncthreads();

    int tt = dir ? (TSEQ - 1) : 0;
    const int tstep = dir ? -1 : 1;
    const int xcol = ks * 128 + j2;   // this thread's gate-ks input column
    float xw = xW_blk[tt * G4 + xcol];

    for (int t = 0; t < TSEQ; ++t) {
        const int p = t & 1;
        const int ttn = tt + tstep;
        float xw_n = 0.f;
        if (t < TSEQ - 1) xw_n = xW_blk[ttn * G4 + xcol];   // prefetch

        float p4[4] = {0.f, 0.f, 0.f, 0.f};
        const float4* hp = (const float4*)&hbuf[p][ks * 40];
        #pragma unroll
        for (int r = 0; r < 8; ++r) {
            const float4 hv = hp[r];
            #pragma unroll
            for (int g = 0; g < 4; ++g)
                p4[g] += hv.x * u[g][4*r]   + hv.y * u[g][4*r+1]
                       + hv.z * u[g][4*r+2] + hv.w * u[g][4*r+3];
        }
        // fold xW into the right gate (static indexing: selects, no scratch)
        #pragma unroll
        for (int g = 0; g < 4; ++g) p4[g] += (ks == g) ? xw : 0.f;

        // butterfly across the 4 ks-partners (lanes tid^1, tid^2: same wave)
        #pragma unroll
        for (int g = 0; g < 4; ++g) p4[g] += __shfl_xor(p4[g], 1);
        #pragma unroll
        for (int g = 0; g < 4; ++g) p4[g] += __shfl_xor(p4[g], 2);

        const float ig = fsig(p4[0]);
        const float fg = fsig(p4[1]);
        const float gg = ftanh(p4[2]);
        const float og = fsig(p4[3]);
        c = fg * c + ig * gg;                    // identical in all 4 partners
        const float h = og * ftanh(c);

        if (ks == 0) {                           // one writer per unit
            hbuf[p ^ 1][j2 + (j2 >> 5) * 8] = h;
            hs_blk[tt * HID + j2] = h;
        }
        __syncthreads();
        xw = xw_n; tt = ttn;
    }
}

// ---------------------------------------------------------------------------
// Kernel C: fold dense + CRF inner kernel: Wd2 = Wd @ crf_W, b2 = bd@crf_W+crf_b
// ---------------------------------------------------------------------------
__global__ void prep_kernel(const float* __restrict__ Wd, const float* __restrict__ bd,
                            const float* __restrict__ crf_W, const float* __restrict__ crf_b,
                            float* __restrict__ Wd2, float* __restrict__ b2)
{
    const int u = threadIdx.x;        // 256 threads
    #pragma unroll
    for (int k = 0; k < KTAG; ++k) {
        float s = 0.f;
        #pragma unroll
        for (int jj = 0; jj < KTAG; ++jj) s += Wd[u * KTAG + jj] * crf_W[jj * KTAG + k];
        Wd2[u * KTAG + k] = s;
    }
    if (u < KTAG) {
        float s = crf_b[u];
        #pragma unroll
        for (int jj = 0; jj < KTAG; ++jj) s += bd[jj] * crf_W[jj * KTAG + u];
        b2[u] = s;
    }
}

// ---------------------------------------------------------------------------
// Kernel D: potentials. One wave per (b,t): pot = [h_f|h_b] @ Wd2 + b2 (+bounds)
// ---------------------------------------------------------------------------
__global__ __launch_bounds__(256) void pot_kernel(
    const float* __restrict__ hs, const float* __restrict__ Wd2,
    const float* __restrict__ b2, const float* __restrict__ left_b,
    const float* __restrict__ right_b, float* __restrict__ pot)
{
    const int wave = blockIdx.x * 4 + (threadIdx.x >> 6);  // (b,t) index
    const int lane = threadIdx.x & 63;
    const int b = wave >> 9, t = wave & 511;

    const float* __restrict__ hf = hs + ((size_t)b * TSEQ + t) * HID;
    const float* __restrict__ hb = hf + (size_t)BATCH * TSEQ * HID;

    const float x0 = hf[lane], x1 = hf[lane + 64];
    const float x2 = hb[lane], x3 = hb[lane + 64];

    float a[KTAG];
    #pragma unroll
    for (int k = 0; k < KTAG; ++k)
        a[k] = x0 * Wd2[lane * KTAG + k] + x1 * Wd2[(lane + 64) * KTAG + k]
             + x2 * Wd2[(lane + 128) * KTAG + k] + x3 * Wd2[(lane + 192) * KTAG + k];

    #pragma unroll
    for (int off = 32; off; off >>= 1) {
        a[0] += __shfl_xor(a[0], off);
        a[1] += __shfl_xor(a[1], off);
        a[2] += __shfl_xor(a[2], off);
    }

    if (lane < KTAG) {
        float v = a[lane] + b2[lane];
        if (t == 0)        v += left_b[lane];
        if (t == TSEQ - 1) v += right_b[lane];
        pot[(size_t)wave * KTAG + lane] = v;
    }
}

// ---------------------------------------------------------------------------
// Kernel E: Viterbi decode, one block per batch. Exact first-max-wins argmax
// semantics (matches jnp.argmax). Backpointers packed 2 bits/state in LDS.
// Decoded tags written as float32.
// ---------------------------------------------------------------------------
__global__ __launch_bounds__(64) void viterbi_kernel(
    const float* __restrict__ pot, const float* __restrict__ chain,
    float* __restrict__ decoded)
{
    const int b = blockIdx.x;
    const int lane = threadIdx.x;

    __shared__ float p[TSEQ][KTAG];
    __shared__ int bp[TSEQ - 1];
    __shared__ unsigned char tags[TSEQ];

    const float* __restrict__ pb = pot + (size_t)b * TSEQ * KTAG;
    for (int i = lane; i < TSEQ * KTAG; i += 64) ((float*)p)[i] = pb[i];
    __syncthreads();

    if (lane == 0) {
        float tr[KTAG][KTAG];
        #pragma unroll
        for (int i = 0; i < 9; ++i) tr[i / 3][i % 3] = chain[i];

        float a0 = p[0][0], a1 = p[0][1], a2 = p[0][2];
        for (int t = 1; t < TSEQ; ++t) {
            float n[KTAG]; int bpk[KTAG];
            #pragma unroll
            for (int kn = 0; kn < KTAG; ++kn) {
                const float s0 = a0 + tr[0][kn];
                const float s1 = a1 + tr[1][kn];
                const float s2 = a2 + tr[2][kn];
                float best = s0; int arg = 0;
                if (s1 > best) { best = s1; arg = 1; }
                if (s2 > best) { best = s2; arg = 2; }
                n[kn] = best + p[t][kn];
                bpk[kn] = arg;
            }
            bp[t - 1] = bpk[0] | (bpk[1] << 2) | (bpk[2] << 4);
            a0 = n[0]; a1 = n[1]; a2 = n[2];
        }
        int tag = 0; float best = a0;
        if (a1 > best) { best = a1; tag = 1; }
        if (a2 > best) { best = a2; tag = 2; }
        tags[TSEQ - 1] = (unsigned char)tag;
        for (int t = TSEQ - 2; t >= 0; --t) {
            tag = (bp[t] >> (2 * tag)) & 3;
            tags[t] = (unsigned char)tag;
        }
    }
    __syncthreads();
    for (int t = lane; t < TSEQ; t += 64)
        decoded[(size_t)b * TSEQ + t] = (float)tags[t];
}

// ---------------------------------------------------------------------------
extern "C" void kernel_launch(void* const* d_in, const int* in_sizes, int n_in,
                              void* d_out, int out_size, void* d_ws, size_t ws_size,
                              hipStream_t stream) {
    const int*   tokens  = (const int*)d_in[0];
    const float* emb     = (const float*)d_in[1];
    const float* Wf      = (const float*)d_in[2];
    const float* Uf      = (const float*)d_in[3];
    const float* bf      = (const float*)d_in[4];
    const float* Wb      = (const float*)d_in[5];
    const float* Ub      = (const float*)d_in[6];
    const float* bb      = (const float*)d_in[7];
    const float* Wd      = (const float*)d_in[8];
    const float* bd      = (const float*)d_in[9];
    const float* crf_W   = (const float*)d_in[10];
    const float* crf_b   = (const float*)d_in[11];
    const float* chain   = (const float*)d_in[12];
    const float* left_b  = (const float*)d_in[13];
    const float* right_b = (const float*)d_in[14];

    float* out = (float*)d_out;                    // [0,32768): decoded, then pot
    float* pot = out + BT;

    float* xW  = (float*)d_ws;                     // 2 * 32768 * 512 f32 = 128 MB
    float* hs  = xW + (size_t)2 * BT * G4;         // 2 * 64 * 512 * 128 f32 = 32 MB
    float* Wd2 = hs + (size_t)2 * BATCH * TSEQ * HID;
    float* b2  = Wd2 + 2 * HID * KTAG;

    dim3 gA(1024 / 128, BT / 128);                 // 8 x 256 blocks
    embed_gemm<<<gA, 256, 0, stream>>>(tokens, emb, Wf, bf, Wb, bb, xW);
    prep_kernel<<<1, 256, 0, stream>>>(Wd, bd, crf_W, crf_b, Wd2, b2);
    lstm_kernel<<<128, 512, 0, stream>>>(Uf, Ub, xW, hs);
    pot_kernel<<<BT / 4, 256, 0, stream>>>(hs, Wd2, b2, left_b, right_b, pot);
    viterbi_kernel<<<BATCH, 64, 0, stream>>>(pot, chain, out);
}

// Round 4
// 773.483 us; speedup vs baseline: 1.5795x; 1.0453x over previous
//
#include <hip/hip_runtime.h>
#include <hip/hip_bf16.h>
#include <math.h>

// Problem constants
#define BATCH 64
#define TSEQ  512
#define BT    (BATCH*TSEQ)      // 32768
#define EDIM  300
#define HID   128
#define G4    512               // 4*H
#define KTAG  3

// ---------------------------------------------------------------------------
// Kernel A: fused embedding gather + input GEMM for both directions.
// (unchanged from round 3 — isolating the LSTM fix this round)
// ---------------------------------------------------------------------------
__global__ __launch_bounds__(256) void embed_gemm(
    const int* __restrict__ tokens, const float* __restrict__ emb,
    const float* __restrict__ Wf, const float* __restrict__ bf,
    const float* __restrict__ Wb, const float* __restrict__ bb,
    float* __restrict__ xW)
{
    const int c0 = blockIdx.x * 128;  // 0..896
    const int m0 = blockIdx.y * 128;
    const int tid = threadIdx.x;

    __shared__ __align__(16) float As[8][132];   // [k][row]
    __shared__ __align__(16) float Bs[8][132];   // [k][col]
    __shared__ int toks[128];

    if (tid < 128) toks[tid] = tokens[m0 + tid];
    __syncthreads();

    const int dir = c0 >> 9;          // whole 128-col tile in one direction
    const float* __restrict__ W    = dir ? Wb : Wf;
    const float* __restrict__ bias = dir ? bb : bf;
    const int j0 = c0 & 511;

    const int tx = tid & 15;          // col group
    const int ty = tid >> 4;          // row group

    float acc[2][2][4][4] = {};       // [mi][nj][r][c]

    for (int k0 = 0; k0 < EDIM; k0 += 8) {
        {
            const int kk = tid & 7, i0 = tid >> 3;
            const int k = k0 + kk;
            #pragma unroll
            for (int rr = 0; rr < 4; ++rr) {
                const int i = i0 + rr * 32;
                As[kk][i] = (k < EDIM) ? emb[(size_t)toks[i] * EDIM + k] : 0.f;
            }
        }
        {
            const int cc = tid & 127, kb = tid >> 7;
            #pragma unroll
            for (int rr = 0; rr < 4; ++rr) {
                const int kk = kb + rr * 2;
                const int k = k0 + kk;
                Bs[kk][cc] = (k < EDIM) ? W[(size_t)k * G4 + j0 + cc] : 0.f;
            }
        }
        __syncthreads();
        #pragma unroll
        for (int kk = 0; kk < 8; ++kk) {
            float a[2][4], b[2][4];
            *(float4*)a[0] = *(const float4*)&As[kk][ty * 4];
            *(float4*)a[1] = *(const float4*)&As[kk][64 + ty * 4];
            *(float4*)b[0] = *(const float4*)&Bs[kk][tx * 4];
            *(float4*)b[1] = *(const float4*)&Bs[kk][64 + tx * 4];
            #pragma unroll
            for (int mi = 0; mi < 2; ++mi)
                #pragma unroll
                for (int nj = 0; nj < 2; ++nj)
                    #pragma unroll
                    for (int r = 0; r < 4; ++r)
                        #pragma unroll
                        for (int cj = 0; cj < 4; ++cj)
                            acc[mi][nj][r][cj] += a[mi][r] * b[nj][cj];
        }
        __syncthreads();
    }

    float4 b4[2];
    b4[0] = *(const float4*)&bias[j0 + tx * 4];
    b4[1] = *(const float4*)&bias[j0 + 64 + tx * 4];
    const size_t obase = (size_t)dir * BT * G4;
    #pragma unroll
    for (int mi = 0; mi < 2; ++mi) {
        #pragma unroll
        for (int r = 0; r < 4; ++r) {
            const int m = m0 + mi * 64 + ty * 4 + r;
            #pragma unroll
            for (int nj = 0; nj < 2; ++nj) {
                const float* bb4 = (const float*)&b4[nj];
                float4 v;
                v.x = acc[mi][nj][r][0] + bb4[0];
                v.y = acc[mi][nj][r][1] + bb4[1];
                v.z = acc[mi][nj][r][2] + bb4[2];
                v.w = acc[mi][nj][r][3] + bb4[3];
                *(float4*)&xW[obase + (size_t)m * G4 + j0 + nj * 64 + tx * 4] = v;
            }
        }
    }
}

// ---------------------------------------------------------------------------
// Fast activations: v_exp_f32 / v_rcp_f32 based, ~1-2 ulp, no libm branches.
// ---------------------------------------------------------------------------
__device__ __forceinline__ float fsig(float x) {
    return __builtin_amdgcn_rcpf(1.f + __expf(-x));
}
__device__ __forceinline__ float ftanh(float x) {
    x = fminf(15.f, fmaxf(-15.f, x));          // avoid inf/inf (|z| << 15 anyway)
    const float e = __expf(2.f * x);
    return (e - 1.f) * __builtin_amdgcn_rcpf(e + 1.f);
}

// ---------------------------------------------------------------------------
// Kernel B: LSTM recurrence, one block per (dir, batch) = 128 blocks.
// 512 threads: thread (j2 = tid>>2, ks = tid&3). Thread owns U rows
// [32ks, 32ks+32) for ALL 4 gates of unit j2.
// Weights held in 128 INDIVIDUALLY-NAMED scalar floats (macro-generated) —
// no arrays, no runtime indexing -> guaranteed VGPR residency (round-3's
// u[4][32] array was demoted; VGPR_Count=84 proved it never lived in regs).
// Per step: 8 ds_read_b128 broadcast of h, 128 FMAs (4 independent chains),
// butterfly over ks-lanes (shfl_xor 1,2), redundant identical activations,
// ONE barrier, double-buffered h, depth-2 xW prefetch.
// ---------------------------------------------------------------------------

// weight declarations: u<g>_<r>
#define DECL_G(g) \
  float u##g##_0,u##g##_1,u##g##_2,u##g##_3,u##g##_4,u##g##_5,u##g##_6,u##g##_7, \
        u##g##_8,u##g##_9,u##g##_10,u##g##_11,u##g##_12,u##g##_13,u##g##_14,u##g##_15, \
        u##g##_16,u##g##_17,u##g##_18,u##g##_19,u##g##_20,u##g##_21,u##g##_22,u##g##_23, \
        u##g##_24,u##g##_25,u##g##_26,u##g##_27,u##g##_28,u##g##_29,u##g##_30,u##g##_31;

#define INIT_G(g) { \
  const float* Ug = U + (size_t)(32 * ks) * G4 + g * 128 + j2; \
  u##g##_0 =Ug[ 0*G4]; u##g##_1 =Ug[ 1*G4]; u##g##_2 =Ug[ 2*G4]; u##g##_3 =Ug[ 3*G4]; \
  u##g##_4 =Ug[ 4*G4]; u##g##_5 =Ug[ 5*G4]; u##g##_6 =Ug[ 6*G4]; u##g##_7 =Ug[ 7*G4]; \
  u##g##_8 =Ug[ 8*G4]; u##g##_9 =Ug[ 9*G4]; u##g##_10=Ug[10*G4]; u##g##_11=Ug[11*G4]; \
  u##g##_12=Ug[12*G4]; u##g##_13=Ug[13*G4]; u##g##_14=Ug[14*G4]; u##g##_15=Ug[15*G4]; \
  u##g##_16=Ug[16*G4]; u##g##_17=Ug[17*G4]; u##g##_18=Ug[18*G4]; u##g##_19=Ug[19*G4]; \
  u##g##_20=Ug[20*G4]; u##g##_21=Ug[21*G4]; u##g##_22=Ug[22*G4]; u##g##_23=Ug[23*G4]; \
  u##g##_24=Ug[24*G4]; u##g##_25=Ug[25*G4]; u##g##_26=Ug[26*G4]; u##g##_27=Ug[27*G4]; \
  u##g##_28=Ug[28*G4]; u##g##_29=Ug[29*G4]; u##g##_30=Ug[30*G4]; u##g##_31=Ug[31*G4]; }

// one float4 of h times 4 gate-weight quads (literal index tokens)
#define MAC4(hv, A, B, C, D) \
  p0 += hv.x*u0_##A + hv.y*u0_##B + hv.z*u0_##C + hv.w*u0_##D; \
  p1 += hv.x*u1_##A + hv.y*u1_##B + hv.z*u1_##C + hv.w*u1_##D; \
  p2 += hv.x*u2_##A + hv.y*u2_##B + hv.z*u2_##C + hv.w*u2_##D; \
  p3 += hv.x*u3_##A + hv.y*u3_##B + hv.z*u3_##C + hv.w*u3_##D;

__global__ __launch_bounds__(512, 2) void lstm_kernel(
    const float* __restrict__ Uf, const float* __restrict__ Ub,
    const float* __restrict__ xW, float* __restrict__ hs)
{
    const int blk = blockIdx.x;       // 0..127
    const int dir = blk >> 6;
    const int tid = threadIdx.x;      // 0..511
    const int j2  = tid >> 2;         // hidden unit 0..127
    const int ks  = tid & 3;          // k-quarter
    const float* __restrict__ U = dir ? Ub : Uf;

    DECL_G(0) DECL_G(1) DECL_G(2) DECL_G(3)
    INIT_G(0) INIT_G(1) INIT_G(2) INIT_G(3)

    // h double buffer; slot(j) = j + (j>>5)*8 keeps the 4 ks-segments on
    // different banks and 16B-aligned
    __shared__ __align__(16) float hbuf[2][160];
    if (tid < 128) hbuf[0][tid + (tid >> 5) * 8] = 0.f;
    float c = 0.f;

    const float* __restrict__ xW_blk = xW + (size_t)blk * (TSEQ * G4);
    float* __restrict__ hs_blk = hs + (size_t)blk * (TSEQ * HID);
    __syncthreads();

    int tt = dir ? (TSEQ - 1) : 0;
    const int tstep = dir ? -1 : 1;
    const int xcol = ks * 128 + j2;   // this thread's gate-ks input column

    // depth-2 prefetch pipeline
    float xw_cur = xW_blk[tt * G4 + xcol];
    float xw_n1  = xW_blk[(tt + tstep) * G4 + xcol];

    for (int t = 0; t < TSEQ; ++t) {
        const int p = t & 1;
        float xw_n2 = 0.f;
        if (t < TSEQ - 2) xw_n2 = xW_blk[(tt + 2 * tstep) * G4 + xcol];

        // init accumulators with xW folded into this thread's own gate
        float p0 = (ks == 0) ? xw_cur : 0.f;
        float p1 = (ks == 1) ? xw_cur : 0.f;
        float p2 = (ks == 2) ? xw_cur : 0.f;
        float p3 = (ks == 3) ? xw_cur : 0.f;

        const float4* hp = (const float4*)&hbuf[p][ks * 40];
        const float4 hA = hp[0], hB = hp[1], hC = hp[2], hD = hp[3];
        const float4 hE = hp[4], hF = hp[5], hG = hp[6], hH = hp[7];
        MAC4(hA, 0, 1, 2, 3)    MAC4(hB, 4, 5, 6, 7)
        MAC4(hC, 8, 9, 10, 11)  MAC4(hD, 12, 13, 14, 15)
        MAC4(hE, 16, 17, 18, 19) MAC4(hF, 20, 21, 22, 23)
        MAC4(hG, 24, 25, 26, 27) MAC4(hH, 28, 29, 30, 31)

        // butterfly across the 4 ks-partners (lanes tid^1, tid^2: same wave)
        p0 += __shfl_xor(p0, 1); p1 += __shfl_xor(p1, 1);
        p2 += __shfl_xor(p2, 1); p3 += __shfl_xor(p3, 1);
        p0 += __shfl_xor(p0, 2); p1 += __shfl_xor(p1, 2);
        p2 += __shfl_xor(p2, 2); p3 += __shfl_xor(p3, 2);

        const float ig = fsig(p0);
        const float fg = fsig(p1);
        const float gg = ftanh(p2);
        const float og = fsig(p3);
        c = fg * c + ig * gg;                    // identical in all 4 partners
        const float h = og * ftanh(c);

        if (ks == 0) {                           // one writer per unit
            hbuf[p ^ 1][j2 + (j2 >> 5) * 8] = h;
            hs_blk[tt * HID + j2] = h;
        }
        __syncthreads();
        xw_cur = xw_n1; xw_n1 = xw_n2; tt += tstep;
    }
}

// ---------------------------------------------------------------------------
// Kernel C: fold dense + CRF inner kernel: Wd2 = Wd @ crf_W, b2 = bd@crf_W+crf_b
// ---------------------------------------------------------------------------
__global__ void prep_kernel(const float* __restrict__ Wd, const float* __restrict__ bd,
                            const float* __restrict__ crf_W, const float* __restrict__ crf_b,
                            float* __restrict__ Wd2, float* __restrict__ b2)
{
    const int u = threadIdx.x;        // 256 threads
    #pragma unroll
    for (int k = 0; k < KTAG; ++k) {
        float s = 0.f;
        #pragma unroll
        for (int jj = 0; jj < KTAG; ++jj) s += Wd[u * KTAG + jj] * crf_W[jj * KTAG + k];
        Wd2[u * KTAG + k] = s;
    }
    if (u < KTAG) {
        float s = crf_b[u];
        #pragma unroll
        for (int jj = 0; jj < KTAG; ++jj) s += bd[jj] * crf_W[jj * KTAG + u];
        b2[u] = s;
    }
}

// ---------------------------------------------------------------------------
// Kernel D: potentials. One wave per (b,t): pot = [h_f|h_b] @ Wd2 + b2 (+bounds)
// ---------------------------------------------------------------------------
__global__ __launch_bounds__(256) void pot_kernel(
    const float* __restrict__ hs, const float* __restrict__ Wd2,
    const float* __restrict__ b2, const float* __restrict__ left_b,
    const float* __restrict__ right_b, float* __restrict__ pot)
{
    const int wave = blockIdx.x * 4 + (threadIdx.x >> 6);  // (b,t) index
    const int lane = threadIdx.x & 63;
    const int b = wave >> 9, t = wave & 511;

    const float* __restrict__ hf = hs + ((size_t)b * TSEQ + t) * HID;
    const float* __restrict__ hb = hf + (size_t)BATCH * TSEQ * HID;

    const float x0 = hf[lane], x1 = hf[lane + 64];
    const float x2 = hb[lane], x3 = hb[lane + 64];

    float a[KTAG];
    #pragma unroll
    for (int k = 0; k < KTAG; ++k)
        a[k] = x0 * Wd2[lane * KTAG + k] + x1 * Wd2[(lane + 64) * KTAG + k]
             + x2 * Wd2[(lane + 128) * KTAG + k] + x3 * Wd2[(lane + 192) * KTAG + k];

    #pragma unroll
    for (int off = 32; off; off >>= 1) {
        a[0] += __shfl_xor(a[0], off);
        a[1] += __shfl_xor(a[1], off);
        a[2] += __shfl_xor(a[2], off);
    }

    if (lane < KTAG) {
        float v = a[lane] + b2[lane];
        if (t == 0)        v += left_b[lane];
        if (t == TSEQ - 1) v += right_b[lane];
        pot[(size_t)wave * KTAG + lane] = v;
    }
}

// ---------------------------------------------------------------------------
// Kernel E: Viterbi decode, one block per batch. Exact first-max-wins argmax
// semantics (matches jnp.argmax). Backpointers packed 2 bits/state in LDS.
// ---------------------------------------------------------------------------
__global__ __launch_bounds__(64) void viterbi_kernel(
    const float* __restrict__ pot, const float* __restrict__ chain,
    float* __restrict__ decoded)
{
    const int b = blockIdx.x;
    const int lane = threadIdx.x;

    __shared__ float p[TSEQ][KTAG];
    __shared__ int bp[TSEQ - 1];
    __shared__ unsigned char tags[TSEQ];

    const float* __restrict__ pb = pot + (size_t)b * TSEQ * KTAG;
    for (int i = lane; i < TSEQ * KTAG; i += 64) ((float*)p)[i] = pb[i];
    __syncthreads();

    if (lane == 0) {
        float tr[KTAG][KTAG];
        #pragma unroll
        for (int i = 0; i < 9; ++i) tr[i / 3][i % 3] = chain[i];

        float a0 = p[0][0], a1 = p[0][1], a2 = p[0][2];
        for (int t = 1; t < TSEQ; ++t) {
            float n[KTAG]; int bpk[KTAG];
            #pragma unroll
            for (int kn = 0; kn < KTAG; ++kn) {
                const float s0 = a0 + tr[0][kn];
                const float s1 = a1 + tr[1][kn];
                const float s2 = a2 + tr[2][kn];
                float best = s0; int arg = 0;
                if (s1 > best) { best = s1; arg = 1; }
                if (s2 > best) { best = s2; arg = 2; }
                n[kn] = best + p[t][kn];
                bpk[kn] = arg;
            }
            bp[t - 1] = bpk[0] | (bpk[1] << 2) | (bpk[2] << 4);
            a0 = n[0]; a1 = n[1]; a2 = n[2];
        }
        int tag = 0; float best = a0;
        if (a1 > best) { best = a1; tag = 1; }
        if (a2 > best) { best = a2; tag = 2; }
        tags[TSEQ - 1] = (unsigned char)tag;
        for (int t = TSEQ - 2; t >= 0; --t) {
            tag = (bp[t] >> (2 * tag)) & 3;
            tags[t] = (unsigned char)tag;
        }
    }
    __syncthreads();
    for (int t = lane; t < TSEQ; t += 64)
        decoded[(size_t)b * TSEQ + t] = (float)tags[t];
}

// ---------------------------------------------------------------------------
extern "C" void kernel_launch(void* const* d_in, const int* in_sizes, int n_in,
                              void* d_out, int out_size, void* d_ws, size_t ws_size,
                              hipStream_t stream) {
    const int*   tokens  = (const int*)d_in[0];
    const float* emb     = (const float*)d_in[1];
    const float* Wf      = (const float*)d_in[2];
    const float* Uf      = (const float*)d_in[3];
    const float* bf      = (const float*)d_in[4];
    const float* Wb      = (const float*)d_in[5];
    const float* Ub      = (const float*)d_in[6];
    const float* bb      = (const float*)d_in[7];
    const float* Wd      = (const float*)d_in[8];
    const float* bd      = (const float*)d_in[9];
    const float* crf_W   = (const float*)d_in[10];
    const float* crf_b   = (const float*)d_in[11];
    const float* chain   = (const float*)d_in[12];
    const float* left_b  = (const float*)d_in[13];
    const float* right_b = (const float*)d_in[14];

    float* out = (float*)d_out;                    // [0,32768): decoded, then pot
    float* pot = out + BT;

    float* xW  = (float*)d_ws;                     // 2 * 32768 * 512 f32 = 128 MB
    float* hs  = xW + (size_t)2 * BT * G4;         // 2 * 64 * 512 * 128 f32 = 32 MB
    float* Wd2 = hs + (size_t)2 * BATCH * TSEQ * HID;
    float* b2  = Wd2 + 2 * HID * KTAG;

    dim3 gA(1024 / 128, BT / 128);                 // 8 x 256 blocks
    embed_gemm<<<gA, 256, 0, stream>>>(tokens, emb, Wf, bf, Wb, bb, xW);
    prep_kernel<<<1, 256, 0, stream>>>(Wd, bd, crf_W, crf_b, Wd2, b2);
    lstm_kernel<<<128, 512, 0, stream>>>(Uf, Ub, xW, hs);
    pot_kernel<<<BT / 4, 256, 0, stream>>>(hs, Wd2, b2, left_b, right_b, pot);
    viterbi_kernel<<<BATCH, 64, 0, stream>>>(pot, chain, out);
}

// Round 5
// 770.170 us; speedup vs baseline: 1.5863x; 1.0043x over previous
//
#include <hip/hip_runtime.h>
#include <hip/hip_bf16.h>
#include <math.h>

// Problem constants
#define BATCH 64
#define TSEQ  512
#define BT    (BATCH*TSEQ)      // 32768
#define EDIM  300
#define HID   128
#define G4    512               // 4*H
#define KTAG  3

// ---------------------------------------------------------------------------
// Kernel A: fused embedding gather + input GEMM for both directions.
// (unchanged — isolating the LSTM register-pin fix this round)
// ---------------------------------------------------------------------------
__global__ __launch_bounds__(256) void embed_gemm(
    const int* __restrict__ tokens, const float* __restrict__ emb,
    const float* __restrict__ Wf, const float* __restrict__ bf,
    const float* __restrict__ Wb, const float* __restrict__ bb,
    float* __restrict__ xW)
{
    const int c0 = blockIdx.x * 128;  // 0..896
    const int m0 = blockIdx.y * 128;
    const int tid = threadIdx.x;

    __shared__ __align__(16) float As[8][132];   // [k][row]
    __shared__ __align__(16) float Bs[8][132];   // [k][col]
    __shared__ int toks[128];

    if (tid < 128) toks[tid] = tokens[m0 + tid];
    __syncthreads();

    const int dir = c0 >> 9;          // whole 128-col tile in one direction
    const float* __restrict__ W    = dir ? Wb : Wf;
    const float* __restrict__ bias = dir ? bb : bf;
    const int j0 = c0 & 511;

    const int tx = tid & 15;          // col group
    const int ty = tid >> 4;          // row group

    float acc[2][2][4][4] = {};       // [mi][nj][r][c]

    for (int k0 = 0; k0 < EDIM; k0 += 8) {
        {
            const int kk = tid & 7, i0 = tid >> 3;
            const int k = k0 + kk;
            #pragma unroll
            for (int rr = 0; rr < 4; ++rr) {
                const int i = i0 + rr * 32;
                As[kk][i] = (k < EDIM) ? emb[(size_t)toks[i] * EDIM + k] : 0.f;
            }
        }
        {
            const int cc = tid & 127, kb = tid >> 7;
            #pragma unroll
            for (int rr = 0; rr < 4; ++rr) {
                const int kk = kb + rr * 2;
                const int k = k0 + kk;
                Bs[kk][cc] = (k < EDIM) ? W[(size_t)k * G4 + j0 + cc] : 0.f;
            }
        }
        __syncthreads();
        #pragma unroll
        for (int kk = 0; kk < 8; ++kk) {
            float a[2][4], b[2][4];
            *(float4*)a[0] = *(const float4*)&As[kk][ty * 4];
            *(float4*)a[1] = *(const float4*)&As[kk][64 + ty * 4];
            *(float4*)b[0] = *(const float4*)&Bs[kk][tx * 4];
            *(float4*)b[1] = *(const float4*)&Bs[kk][64 + tx * 4];
            #pragma unroll
            for (int mi = 0; mi < 2; ++mi)
                #pragma unroll
                for (int nj = 0; nj < 2; ++nj)
                    #pragma unroll
                    for (int r = 0; r < 4; ++r)
                        #pragma unroll
                        for (int cj = 0; cj < 4; ++cj)
                            acc[mi][nj][r][cj] += a[mi][r] * b[nj][cj];
        }
        __syncthreads();
    }

    float4 b4[2];
    b4[0] = *(const float4*)&bias[j0 + tx * 4];
    b4[1] = *(const float4*)&bias[j0 + 64 + tx * 4];
    const size_t obase = (size_t)dir * BT * G4;
    #pragma unroll
    for (int mi = 0; mi < 2; ++mi) {
        #pragma unroll
        for (int r = 0; r < 4; ++r) {
            const int m = m0 + mi * 64 + ty * 4 + r;
            #pragma unroll
            for (int nj = 0; nj < 2; ++nj) {
                const float* bb4 = (const float*)&b4[nj];
                float4 v;
                v.x = acc[mi][nj][r][0] + bb4[0];
                v.y = acc[mi][nj][r][1] + bb4[1];
                v.z = acc[mi][nj][r][2] + bb4[2];
                v.w = acc[mi][nj][r][3] + bb4[3];
                *(float4*)&xW[obase + (size_t)m * G4 + j0 + nj * 64 + tx * 4] = v;
            }
        }
    }
}

// ---------------------------------------------------------------------------
// Fast activations: v_exp_f32 / v_rcp_f32 based, ~1-2 ulp, no libm branches.
// ---------------------------------------------------------------------------
__device__ __forceinline__ float fsig(float x) {
    return __builtin_amdgcn_rcpf(1.f + __expf(-x));
}
__device__ __forceinline__ float ftanh(float x) {
    x = fminf(15.f, fmaxf(-15.f, x));          // avoid inf/inf (|z| << 15 anyway)
    const float e = __expf(2.f * x);
    return (e - 1.f) * __builtin_amdgcn_rcpf(e + 1.f);
}

// ---------------------------------------------------------------------------
// Kernel B: LSTM recurrence, one block per (dir, batch) = 128 blocks.
// 512 threads: thread (j2 = tid>>2, ks = tid&3) owns U rows [32ks,32ks+32)
// for all 4 gates of unit j2 = 128 weight scalars.
// KEY FIX (round 5): rounds 3-4 showed VGPR_Count=84 — the compiler
// REMATERIALIZED the weight loads inside the t-loop (re-reading 32 MB/step
// from L2 = the whole 475 us). The asm volatile "+v" pins below make the
// weights asm-defined values the allocator MUST keep in VGPRs.
// ---------------------------------------------------------------------------

#define DECL_G(g) \
  float u##g##_0,u##g##_1,u##g##_2,u##g##_3,u##g##_4,u##g##_5,u##g##_6,u##g##_7, \
        u##g##_8,u##g##_9,u##g##_10,u##g##_11,u##g##_12,u##g##_13,u##g##_14,u##g##_15, \
        u##g##_16,u##g##_17,u##g##_18,u##g##_19,u##g##_20,u##g##_21,u##g##_22,u##g##_23, \
        u##g##_24,u##g##_25,u##g##_26,u##g##_27,u##g##_28,u##g##_29,u##g##_30,u##g##_31;

#define INIT_G(g) { \
  const float* Ug = U + (size_t)(32 * ks) * G4 + g * 128 + j2; \
  u##g##_0 =Ug[ 0*G4]; u##g##_1 =Ug[ 1*G4]; u##g##_2 =Ug[ 2*G4]; u##g##_3 =Ug[ 3*G4]; \
  u##g##_4 =Ug[ 4*G4]; u##g##_5 =Ug[ 5*G4]; u##g##_6 =Ug[ 6*G4]; u##g##_7 =Ug[ 7*G4]; \
  u##g##_8 =Ug[ 8*G4]; u##g##_9 =Ug[ 9*G4]; u##g##_10=Ug[10*G4]; u##g##_11=Ug[11*G4]; \
  u##g##_12=Ug[12*G4]; u##g##_13=Ug[13*G4]; u##g##_14=Ug[14*G4]; u##g##_15=Ug[15*G4]; \
  u##g##_16=Ug[16*G4]; u##g##_17=Ug[17*G4]; u##g##_18=Ug[18*G4]; u##g##_19=Ug[19*G4]; \
  u##g##_20=Ug[20*G4]; u##g##_21=Ug[21*G4]; u##g##_22=Ug[22*G4]; u##g##_23=Ug[23*G4]; \
  u##g##_24=Ug[24*G4]; u##g##_25=Ug[25*G4]; u##g##_26=Ug[26*G4]; u##g##_27=Ug[27*G4]; \
  u##g##_28=Ug[28*G4]; u##g##_29=Ug[29*G4]; u##g##_30=Ug[30*G4]; u##g##_31=Ug[31*G4]; }

// opaque pin: weights become asm-defined -> cannot be rematerialized/sunk
#define PIN_G(g) \
  asm volatile("" : "+v"(u##g##_0),"+v"(u##g##_1),"+v"(u##g##_2),"+v"(u##g##_3), \
                    "+v"(u##g##_4),"+v"(u##g##_5),"+v"(u##g##_6),"+v"(u##g##_7), \
                    "+v"(u##g##_8),"+v"(u##g##_9),"+v"(u##g##_10),"+v"(u##g##_11), \
                    "+v"(u##g##_12),"+v"(u##g##_13),"+v"(u##g##_14),"+v"(u##g##_15)); \
  asm volatile("" : "+v"(u##g##_16),"+v"(u##g##_17),"+v"(u##g##_18),"+v"(u##g##_19), \
                    "+v"(u##g##_20),"+v"(u##g##_21),"+v"(u##g##_22),"+v"(u##g##_23), \
                    "+v"(u##g##_24),"+v"(u##g##_25),"+v"(u##g##_26),"+v"(u##g##_27), \
                    "+v"(u##g##_28),"+v"(u##g##_29),"+v"(u##g##_30),"+v"(u##g##_31));

#define MAC4(hv, A, B, C, D) \
  p0 += hv.x*u0_##A + hv.y*u0_##B + hv.z*u0_##C + hv.w*u0_##D; \
  p1 += hv.x*u1_##A + hv.y*u1_##B + hv.z*u1_##C + hv.w*u1_##D; \
  p2 += hv.x*u2_##A + hv.y*u2_##B + hv.z*u2_##C + hv.w*u2_##D; \
  p3 += hv.x*u3_##A + hv.y*u3_##B + hv.z*u3_##C + hv.w*u3_##D;

__global__ __launch_bounds__(512, 2) void lstm_kernel(
    const float* __restrict__ Uf, const float* __restrict__ Ub,
    const float* __restrict__ xW, float* __restrict__ hs)
{
    const int blk = blockIdx.x;       // 0..127
    const int dir = blk >> 6;
    const int tid = threadIdx.x;      // 0..511
    const int j2  = tid >> 2;         // hidden unit 0..127
    const int ks  = tid & 3;          // k-quarter
    const float* __restrict__ U = dir ? Ub : Uf;

    DECL_G(0) DECL_G(1) DECL_G(2) DECL_G(3)
    INIT_G(0) INIT_G(1) INIT_G(2) INIT_G(3)
    PIN_G(0) PIN_G(1) PIN_G(2) PIN_G(3)

    // h double buffer; slot(j) = j + (j>>5)*8 keeps the 4 ks-segments on
    // different banks and 16B-aligned
    __shared__ __align__(16) float hbuf[2][160];
    if (tid < 128) hbuf[0][tid + (tid >> 5) * 8] = 0.f;
    float c = 0.f;

    const float* __restrict__ xW_blk = xW + (size_t)blk * (TSEQ * G4);
    float* __restrict__ hs_blk = hs + (size_t)blk * (TSEQ * HID);
    __syncthreads();

    int tt = dir ? (TSEQ - 1) : 0;
    const int tstep = dir ? -1 : 1;
    const int xcol = ks * 128 + j2;   // this thread's gate-ks input column

    // depth-2 prefetch pipeline
    float xw_cur = xW_blk[tt * G4 + xcol];
    float xw_n1  = xW_blk[(tt + tstep) * G4 + xcol];

    for (int t = 0; t < TSEQ; ++t) {
        const int p = t & 1;
        float xw_n2 = 0.f;
        if (t < TSEQ - 2) xw_n2 = xW_blk[(tt + 2 * tstep) * G4 + xcol];

        // init accumulators with xW folded into this thread's own gate
        float p0 = (ks == 0) ? xw_cur : 0.f;
        float p1 = (ks == 1) ? xw_cur : 0.f;
        float p2 = (ks == 2) ? xw_cur : 0.f;
        float p3 = (ks == 3) ? xw_cur : 0.f;

        const float4* hp = (const float4*)&hbuf[p][ks * 40];
        const float4 hA = hp[0], hB = hp[1], hC = hp[2], hD = hp[3];
        const float4 hE = hp[4], hF = hp[5], hG = hp[6], hH = hp[7];
        MAC4(hA, 0, 1, 2, 3)    MAC4(hB, 4, 5, 6, 7)
        MAC4(hC, 8, 9, 10, 11)  MAC4(hD, 12, 13, 14, 15)
        MAC4(hE, 16, 17, 18, 19) MAC4(hF, 20, 21, 22, 23)
        MAC4(hG, 24, 25, 26, 27) MAC4(hH, 28, 29, 30, 31)

        // butterfly across the 4 ks-partners (lanes tid^1, tid^2: same wave)
        p0 += __shfl_xor(p0, 1); p1 += __shfl_xor(p1, 1);
        p2 += __shfl_xor(p2, 1); p3 += __shfl_xor(p3, 1);
        p0 += __shfl_xor(p0, 2); p1 += __shfl_xor(p1, 2);
        p2 += __shfl_xor(p2, 2); p3 += __shfl_xor(p3, 2);

        const float ig = fsig(p0);
        const float fg = fsig(p1);
        const float gg = ftanh(p2);
        const float og = fsig(p3);
        c = fg * c + ig * gg;                    // identical in all 4 partners
        const float h = og * ftanh(c);

        if (ks == 0) {                           // one writer per unit
            hbuf[p ^ 1][j2 + (j2 >> 5) * 8] = h;
            hs_blk[tt * HID + j2] = h;
        }
        __syncthreads();
        xw_cur = xw_n1; xw_n1 = xw_n2; tt += tstep;
    }
}

// ---------------------------------------------------------------------------
// Kernel C: fold dense + CRF inner kernel: Wd2 = Wd @ crf_W, b2 = bd@crf_W+crf_b
// ---------------------------------------------------------------------------
__global__ void prep_kernel(const float* __restrict__ Wd, const float* __restrict__ bd,
                            const float* __restrict__ crf_W, const float* __restrict__ crf_b,
                            float* __restrict__ Wd2, float* __restrict__ b2)
{
    const int u = threadIdx.x;        // 256 threads
    #pragma unroll
    for (int k = 0; k < KTAG; ++k) {
        float s = 0.f;
        #pragma unroll
        for (int jj = 0; jj < KTAG; ++jj) s += Wd[u * KTAG + jj] * crf_W[jj * KTAG + k];
        Wd2[u * KTAG + k] = s;
    }
    if (u < KTAG) {
        float s = crf_b[u];
        #pragma unroll
        for (int jj = 0; jj < KTAG; ++jj) s += bd[jj] * crf_W[jj * KTAG + u];
        b2[u] = s;
    }
}

// ---------------------------------------------------------------------------
// Kernel D: potentials. One wave per (b,t): pot = [h_f|h_b] @ Wd2 + b2 (+bounds)
// ---------------------------------------------------------------------------
__global__ __launch_bounds__(256) void pot_kernel(
    const float* __restrict__ hs, const float* __restrict__ Wd2,
    const float* __restrict__ b2, const float* __restrict__ left_b,
    const float* __restrict__ right_b, float* __restrict__ pot)
{
    const int wave = blockIdx.x * 4 + (threadIdx.x >> 6);  // (b,t) index
    const int lane = threadIdx.x & 63;
    const int b = wave >> 9, t = wave & 511;

    const float* __restrict__ hf = hs + ((size_t)b * TSEQ + t) * HID;
    const float* __restrict__ hb = hf + (size_t)BATCH * TSEQ * HID;

    const float x0 = hf[lane], x1 = hf[lane + 64];
    const float x2 = hb[lane], x3 = hb[lane + 64];

    float a[KTAG];
    #pragma unroll
    for (int k = 0; k < KTAG; ++k)
        a[k] = x0 * Wd2[lane * KTAG + k] + x1 * Wd2[(lane + 64) * KTAG + k]
             + x2 * Wd2[(lane + 128) * KTAG + k] + x3 * Wd2[(lane + 192) * KTAG + k];

    #pragma unroll
    for (int off = 32; off; off >>= 1) {
        a[0] += __shfl_xor(a[0], off);
        a[1] += __shfl_xor(a[1], off);
        a[2] += __shfl_xor(a[2], off);
    }

    if (lane < KTAG) {
        float v = a[lane] + b2[lane];
        if (t == 0)        v += left_b[lane];
        if (t == TSEQ - 1) v += right_b[lane];
        pot[(size_t)wave * KTAG + lane] = v;
    }
}

// ---------------------------------------------------------------------------
// Kernel E: Viterbi decode, one block per batch. Exact first-max-wins argmax
// semantics (matches jnp.argmax). Backpointers packed 2 bits/state in LDS.
// ---------------------------------------------------------------------------
__global__ __launch_bounds__(64) void viterbi_kernel(
    const float* __restrict__ pot, const float* __restrict__ chain,
    float* __restrict__ decoded)
{
    const int b = blockIdx.x;
    const int lane = threadIdx.x;

    __shared__ float p[TSEQ][KTAG];
    __shared__ int bp[TSEQ - 1];
    __shared__ unsigned char tags[TSEQ];

    const float* __restrict__ pb = pot + (size_t)b * TSEQ * KTAG;
    for (int i = lane; i < TSEQ * KTAG; i += 64) ((float*)p)[i] = pb[i];
    __syncthreads();

    if (lane == 0) {
        float tr[KTAG][KTAG];
        #pragma unroll
        for (int i = 0; i < 9; ++i) tr[i / 3][i % 3] = chain[i];

        float a0 = p[0][0], a1 = p[0][1], a2 = p[0][2];
        for (int t = 1; t < TSEQ; ++t) {
            float n[KTAG]; int bpk[KTAG];
            #pragma unroll
            for (int kn = 0; kn < KTAG; ++kn) {
                const float s0 = a0 + tr[0][kn];
                const float s1 = a1 + tr[1][kn];
                const float s2 = a2 + tr[2][kn];
                float best = s0; int arg = 0;
                if (s1 > best) { best = s1; arg = 1; }
                if (s2 > best) { best = s2; arg = 2; }
                n[kn] = best + p[t][kn];
                bpk[kn] = arg;
            }
            bp[t - 1] = bpk[0] | (bpk[1] << 2) | (bpk[2] << 4);
            a0 = n[0]; a1 = n[1]; a2 = n[2];
        }
        int tag = 0; float best = a0;
        if (a1 > best) { best = a1; tag = 1; }
        if (a2 > best) { best = a2; tag = 2; }
        tags[TSEQ - 1] = (unsigned char)tag;
        for (int t = TSEQ - 2; t >= 0; --t) {
            tag = (bp[t] >> (2 * tag)) & 3;
            tags[t] = (unsigned char)tag;
        }
    }
    __syncthreads();
    for (int t = lane; t < TSEQ; t += 64)
        decoded[(size_t)b * TSEQ + t] = (float)tags[t];
}

// ---------------------------------------------------------------------------
extern "C" void kernel_launch(void* const* d_in, const int* in_sizes, int n_in,
                              void* d_out, int out_size, void* d_ws, size_t ws_size,
                              hipStream_t stream) {
    const int*   tokens  = (const int*)d_in[0];
    const float* emb     = (const float*)d_in[1];
    const float* Wf      = (const float*)d_in[2];
    const float* Uf      = (const float*)d_in[3];
    const float* bf      = (const float*)d_in[4];
    const float* Wb      = (const float*)d_in[5];
    const float* Ub      = (const float*)d_in[6];
    const float* bb      = (const float*)d_in[7];
    const float* Wd      = (const float*)d_in[8];
    const float* bd      = (const float*)d_in[9];
    const float* crf_W   = (const float*)d_in[10];
    const float* crf_b   = (const float*)d_in[11];
    const float* chain   = (const float*)d_in[12];
    const float* left_b  = (const float*)d_in[13];
    const float* right_b = (const float*)d_in[14];

    float* out = (float*)d_out;                    // [0,32768): decoded, then pot
    float* pot = out + BT;

    float* xW  = (float*)d_ws;                     // 2 * 32768 * 512 f32 = 128 MB
    float* hs  = xW + (size_t)2 * BT * G4;         // 2 * 64 * 512 * 128 f32 = 32 MB
    float* Wd2 = hs + (size_t)2 * BATCH * TSEQ * HID;
    float* b2  = Wd2 + 2 * HID * KTAG;

    dim3 gA(1024 / 128, BT / 128);                 // 8 x 256 blocks
    embed_gemm<<<gA, 256, 0, stream>>>(tokens, emb, Wf, bf, Wb, bb, xW);
    prep_kernel<<<1, 256, 0, stream>>>(Wd, bd, crf_W, crf_b, Wd2, b2);
    lstm_kernel<<<128, 512, 0, stream>>>(Uf, Ub, xW, hs);
    pot_kernel<<<BT / 4, 256, 0, stream>>>(hs, Wd2, b2, left_b, right_b, pot);
    viterbi_kernel<<<BATCH, 64, 0, stream>>>(pot, chain, out);
}